// Round 1
// baseline (848.189 us; speedup 1.0000x reference)
//
#include <hip/hip_runtime.h>

// SGConv (K=2, two layers) on MI355X.
// Pipeline: deg/dinv -> CSR(by dst) -> hop x2 -> linear64+relu -> hop x2 -> linear40.
// Hops are gather-formulated: 1 wave per dst node, lane = feature (64 feats).
// Self-loop handled analytically: acc = dinv[d]^2 * x[d] + sum_e val[e]*x[col[e]].

__global__ __launch_bounds__(256) void init_kernel(float* deg, int* cnt, int N_) {
    int n = blockIdx.x * blockDim.x + threadIdx.x;
    if (n < N_) { deg[n] = 1.0f; cnt[n] = 0; }   // self-loop weight 1 pre-added
}

__global__ __launch_bounds__(256) void deg_count_kernel(const int* __restrict__ ei,
                                                        const float* __restrict__ w,
                                                        float* deg, int* cnt, int E_) {
    int e = blockIdx.x * blockDim.x + threadIdx.x;
    if (e < E_) {
        int d = ei[E_ + e];              // edge_index[1][e] = dst
        atomicAdd(&deg[d], w[e]);
        atomicAdd(&cnt[d], 1);
    }
}

__global__ __launch_bounds__(256) void rsqrt_kernel(float* deg, int N_) {
    int n = blockIdx.x * blockDim.x + threadIdx.x;
    if (n < N_) {
        float dg = deg[n];
        deg[n] = (dg > 0.f) ? (1.0f / sqrtf(dg)) : 0.f;   // in-place -> dinv
    }
}

// Single-block exclusive scan of cnt[0..N) into row_ptr[0..N]; zeroes cnt (reused as cursor).
__global__ __launch_bounds__(1024) void scan_kernel(int* cnt, int* row_ptr, int N_) {
    const int TPB = 1024, PER = 32, CHUNK = TPB * PER;
    __shared__ int sm[TPB];
    __shared__ int carry;
    int tid = threadIdx.x;
    if (tid == 0) carry = 0;
    __syncthreads();
    for (int base = 0; base < N_; base += CHUNK) {
        int loc[PER];
        int sum = 0;
        #pragma unroll
        for (int j = 0; j < PER; ++j) {
            int i = base + tid * PER + j;
            int c = (i < N_) ? cnt[i] : 0;
            if (i < N_) cnt[i] = 0;
            loc[j] = sum;            // local exclusive prefix
            sum += c;
        }
        sm[tid] = sum;
        __syncthreads();
        for (int ofs = 1; ofs < TPB; ofs <<= 1) {
            int v = (tid >= ofs) ? sm[tid - ofs] : 0;
            __syncthreads();
            sm[tid] += v;
            __syncthreads();
        }
        int texcl = carry + sm[tid] - sum;   // exclusive prefix of this thread's segment
        #pragma unroll
        for (int j = 0; j < PER; ++j) {
            int i = base + tid * PER + j;
            if (i < N_) row_ptr[i] = texcl + loc[j];
        }
        __syncthreads();
        if (tid == TPB - 1) carry += sm[TPB - 1];
        __syncthreads();
    }
    if (tid == 0) row_ptr[N_] = carry;
}

__global__ __launch_bounds__(256) void csr_fill_kernel(const int* __restrict__ ei,
                                                       const float* __restrict__ w,
                                                       const float* __restrict__ dinv,
                                                       const int* __restrict__ row_ptr,
                                                       int* cursor,
                                                       int* __restrict__ col,
                                                       float* __restrict__ val, int E_) {
    int e = blockIdx.x * blockDim.x + threadIdx.x;
    if (e < E_) {
        int s = ei[e];
        int d = ei[E_ + e];
        int pos = row_ptr[d] + atomicAdd(&cursor[d], 1);
        col[pos] = s;
        val[pos] = dinv[s] * w[e] * dinv[d];
    }
}

// One wave per dst node; lane = feature (64 features).
__global__ __launch_bounds__(256) void hop_kernel(const float* __restrict__ xin,
                                                  float* __restrict__ xout,
                                                  const float* __restrict__ dinv,
                                                  const int* __restrict__ row_ptr,
                                                  const int* __restrict__ col,
                                                  const float* __restrict__ val, int N_) {
    int wave = (blockIdx.x * blockDim.x + threadIdx.x) >> 6;
    int lane = threadIdx.x & 63;
    if (wave >= N_) return;
    int d = wave;
    float di = dinv[d];
    float acc = di * di * xin[(size_t)d * 64 + lane];   // self-loop
    int e  = row_ptr[d];
    int e1 = row_ptr[d + 1];
    // unroll-by-2 so two gather loads are in flight per iteration
    for (; e + 1 < e1; e += 2) {
        int   s0 = col[e],     s1 = col[e + 1];
        float v0 = val[e],     v1 = val[e + 1];
        float x0 = xin[(size_t)s0 * 64 + lane];
        float x1 = xin[(size_t)s1 * 64 + lane];
        acc = fmaf(v0, x0, acc);
        acc = fmaf(v1, x1, acc);
    }
    if (e < e1) {
        int s = col[e];
        acc = fmaf(val[e], xin[(size_t)s * 64 + lane], acc);
    }
    xout[(size_t)d * 64 + lane] = acc;
}

// out[n][f] = relu( sum_k h[n][k] * W[f][k] + b[f] ), 64x64. One wave per node iter.
__global__ __launch_bounds__(256) void linear64_relu_kernel(const float* __restrict__ hin,
                                                            float* __restrict__ hout,
                                                            const float* __restrict__ W,
                                                            const float* __restrict__ b, int N_) {
    __shared__ float wl[64 * 65];   // pitch 65: bank = (lane+k)%32 -> conflict-free
    __shared__ float bl[64];
    for (int i = threadIdx.x; i < 64 * 64; i += 256) wl[(i >> 6) * 65 + (i & 63)] = W[i];
    if (threadIdx.x < 64) bl[threadIdx.x] = b[threadIdx.x];
    __syncthreads();
    int lane = threadIdx.x & 63;
    int gw = (blockIdx.x * blockDim.x + threadIdx.x) >> 6;
    int nw = (gridDim.x * blockDim.x) >> 6;
    for (int n = gw; n < N_; n += nw) {
        float hv = hin[(size_t)n * 64 + lane];
        float acc = bl[lane];
        #pragma unroll
        for (int k = 0; k < 64; ++k)
            acc = fmaf(__shfl(hv, k), wl[lane * 65 + k], acc);
        hout[(size_t)n * 64 + lane] = fmaxf(acc, 0.f);
    }
}

// out[n][f] = sum_k h[n][k] * W[f][k] + b[f], F_ <= 64 outputs.
__global__ __launch_bounds__(256) void linear_out_kernel(const float* __restrict__ hin,
                                                         float* __restrict__ out,
                                                         const float* __restrict__ W,
                                                         const float* __restrict__ b,
                                                         int N_, int F_) {
    __shared__ float wl[64 * 65];
    __shared__ float bl[64];
    for (int i = threadIdx.x; i < 64 * 65; i += 256) wl[i] = 0.f;   // zero pad rows >= F_
    __syncthreads();
    for (int i = threadIdx.x; i < F_ * 64; i += 256) wl[(i >> 6) * 65 + (i & 63)] = W[i];
    if (threadIdx.x < 64) bl[threadIdx.x] = (threadIdx.x < F_) ? b[threadIdx.x] : 0.f;
    __syncthreads();
    int lane = threadIdx.x & 63;
    int gw = (blockIdx.x * blockDim.x + threadIdx.x) >> 6;
    int nw = (gridDim.x * blockDim.x) >> 6;
    for (int n = gw; n < N_; n += nw) {
        float hv = hin[(size_t)n * 64 + lane];
        float acc = bl[lane];
        #pragma unroll
        for (int k = 0; k < 64; ++k)
            acc = fmaf(__shfl(hv, k), wl[lane * 65 + k], acc);
        if (lane < F_) out[(size_t)n * F_ + lane] = acc;
    }
}

extern "C" void kernel_launch(void* const* d_in, const int* in_sizes, int n_in,
                              void* d_out, int out_size, void* d_ws, size_t ws_size,
                              hipStream_t stream) {
    const float* x   = (const float*)d_in[0];
    const int*   ei  = (const int*)d_in[1];
    const float* w   = (const float*)d_in[2];
    const float* W1  = (const float*)d_in[3];
    const float* b1  = (const float*)d_in[4];
    const float* W2  = (const float*)d_in[5];
    const float* b2  = (const float*)d_in[6];
    float* out = (float*)d_out;

    const int N_ = in_sizes[0] / 64;        // 100000
    const int E_ = in_sizes[2];             // 1200000
    const int F_ = in_sizes[5] / 64;        // 40

    char* ws = (char*)d_ws;
    size_t off = 0;
    auto alloc = [&](size_t bytes) { size_t o = off; off += (bytes + 255) & ~(size_t)255; return o; };
    float* dinv    = (float*)(ws + alloc((size_t)N_ * 4));
    int*   cnt     = (int*)  (ws + alloc((size_t)N_ * 4));
    int*   row_ptr = (int*)  (ws + alloc(((size_t)N_ + 1) * 4));
    int*   col     = (int*)  (ws + alloc((size_t)E_ * 4));
    float* val     = (float*)(ws + alloc((size_t)E_ * 4));
    float* bufA    = (float*)(ws + alloc((size_t)N_ * 64 * 4));
    float* bufB    = (float*)(ws + alloc((size_t)N_ * 64 * 4));
    (void)ws_size; (void)n_in; (void)out_size;

    const int bn = (N_ + 255) / 256;
    const int be = (E_ + 255) / 256;
    const int bh = (N_ + 3) / 4;            // 4 waves (nodes) per 256-thread block

    init_kernel<<<bn, 256, 0, stream>>>(dinv, cnt, N_);
    deg_count_kernel<<<be, 256, 0, stream>>>(ei, w, dinv, cnt, E_);
    rsqrt_kernel<<<bn, 256, 0, stream>>>(dinv, N_);
    scan_kernel<<<1, 1024, 0, stream>>>(cnt, row_ptr, N_);
    csr_fill_kernel<<<be, 256, 0, stream>>>(ei, w, dinv, row_ptr, cnt, col, val, E_);

    hop_kernel<<<bh, 256, 0, stream>>>(x,    bufA, dinv, row_ptr, col, val, N_);
    hop_kernel<<<bh, 256, 0, stream>>>(bufA, bufB, dinv, row_ptr, col, val, N_);
    linear64_relu_kernel<<<1024, 256, 0, stream>>>(bufB, bufA, W1, b1, N_);
    hop_kernel<<<bh, 256, 0, stream>>>(bufA, bufB, dinv, row_ptr, col, val, N_);
    hop_kernel<<<bh, 256, 0, stream>>>(bufB, bufA, dinv, row_ptr, col, val, N_);
    linear_out_kernel<<<1024, 256, 0, stream>>>(bufA, out, W2, b2, N_, F_);
}

// Round 2
// 559.235 us; speedup vs baseline: 1.5167x; 1.5167x over previous
//
#include <hip/hip_runtime.h>

// SGConv (K=2, two layers) on MI355X.
// Pipeline: deg/dinv -> CSR(by dst) -> hop x2 -> linear64+relu -> hop x2 -> linear40.
// Hops are gather-formulated: 1 wave per dst node, lane = feature (64 feats).
// Self-loop handled analytically: acc = dinv[d]^2 * x[d] + sum_e val[e]*x[col[e]].
// R1: multi-block scan (was 192us single-block -> ~8us), hop edge-preload+shfl + unroll-4.

#define SCAN_TPB 256
#define SCAN_ITEMS 8
#define SCAN_CHUNK (SCAN_TPB * SCAN_ITEMS)   // 2048 elements per block

__global__ __launch_bounds__(256) void init_kernel(float* deg, int* cnt, int N_) {
    int n = blockIdx.x * blockDim.x + threadIdx.x;
    if (n < N_) { deg[n] = 1.0f; cnt[n] = 0; }   // self-loop weight 1 pre-added
}

__global__ __launch_bounds__(256) void deg_count_kernel(const int* __restrict__ ei,
                                                        const float* __restrict__ w,
                                                        float* deg, int* cnt, int E_) {
    int e = blockIdx.x * blockDim.x + threadIdx.x;
    if (e < E_) {
        int d = ei[E_ + e];              // edge_index[1][e] = dst
        atomicAdd(&deg[d], w[e]);
        atomicAdd(&cnt[d], 1);
    }
}

__global__ __launch_bounds__(256) void rsqrt_kernel(float* deg, int N_) {
    int n = blockIdx.x * blockDim.x + threadIdx.x;
    if (n < N_) {
        float dg = deg[n];
        deg[n] = (dg > 0.f) ? (1.0f / sqrtf(dg)) : 0.f;   // in-place -> dinv
    }
}

// --- 3-phase hierarchical exclusive scan of cnt -> row_ptr; zeroes cnt ---

__global__ __launch_bounds__(SCAN_TPB) void scan_partial_kernel(const int* __restrict__ cnt,
                                                                int* __restrict__ bsums, int N_) {
    int t = threadIdx.x;
    int base = blockIdx.x * SCAN_CHUNK + t * SCAN_ITEMS;
    int s = 0;
    #pragma unroll
    for (int j = 0; j < SCAN_ITEMS; ++j) { int i = base + j; if (i < N_) s += cnt[i]; }
    __shared__ int sm[SCAN_TPB];
    sm[t] = s; __syncthreads();
    for (int o = SCAN_TPB / 2; o > 0; o >>= 1) {
        if (t < o) sm[t] += sm[t + o];
        __syncthreads();
    }
    if (t == 0) bsums[blockIdx.x] = sm[0];
}

__global__ __launch_bounds__(1024) void scan_bsums_kernel(int* bsums, int nb,
                                                          int* row_ptr, int N_) {
    __shared__ int sm[1024];
    int t = threadIdx.x;
    int v = (t < nb) ? bsums[t] : 0;
    sm[t] = v; __syncthreads();
    for (int o = 1; o < 1024; o <<= 1) {
        int u = (t >= o) ? sm[t - o] : 0;
        __syncthreads();
        sm[t] += u;
        __syncthreads();
    }
    if (t < nb) bsums[t] = sm[t] - v;          // exclusive block offset
    if (t == 1023) row_ptr[N_] = sm[1023];     // grand total
}

__global__ __launch_bounds__(SCAN_TPB) void scan_final_kernel(int* __restrict__ cnt,
                                                              const int* __restrict__ bsums,
                                                              int* __restrict__ row_ptr, int N_) {
    int t = threadIdx.x;
    int base = blockIdx.x * SCAN_CHUNK + t * SCAN_ITEMS;
    int loc[SCAN_ITEMS];
    int s = 0;
    #pragma unroll
    for (int j = 0; j < SCAN_ITEMS; ++j) {
        int i = base + j;
        int c = (i < N_) ? cnt[i] : 0;
        if (i < N_) cnt[i] = 0;                // reset for cursor reuse
        loc[j] = s; s += c;
    }
    __shared__ int sm[SCAN_TPB];
    sm[t] = s; __syncthreads();
    for (int o = 1; o < SCAN_TPB; o <<= 1) {
        int u = (t >= o) ? sm[t - o] : 0;
        __syncthreads();
        sm[t] += u;
        __syncthreads();
    }
    int excl = bsums[blockIdx.x] + sm[t] - s;
    #pragma unroll
    for (int j = 0; j < SCAN_ITEMS; ++j) {
        int i = base + j;
        if (i < N_) row_ptr[i] = excl + loc[j];
    }
}

__global__ __launch_bounds__(256) void csr_fill_kernel(const int* __restrict__ ei,
                                                       const float* __restrict__ w,
                                                       const float* __restrict__ dinv,
                                                       const int* __restrict__ row_ptr,
                                                       int* cursor,
                                                       int* __restrict__ col,
                                                       float* __restrict__ val, int E_) {
    int e = blockIdx.x * blockDim.x + threadIdx.x;
    if (e < E_) {
        int s = ei[e];
        int d = ei[E_ + e];
        int pos = row_ptr[d] + atomicAdd(&cursor[d], 1);
        col[pos] = s;
        val[pos] = dinv[s] * w[e] * dinv[d];
    }
}

// One wave per dst node; lane = feature (64 features).
// Edge list bulk-loaded 64-wide across lanes, broadcast via __shfl; gathers unrolled x4.
__global__ __launch_bounds__(256) void hop_kernel(const float* __restrict__ xin,
                                                  float* __restrict__ xout,
                                                  const float* __restrict__ dinv,
                                                  const int* __restrict__ row_ptr,
                                                  const int* __restrict__ col,
                                                  const float* __restrict__ val, int N_) {
    int wave = (blockIdx.x * blockDim.x + threadIdx.x) >> 6;
    int lane = threadIdx.x & 63;
    if (wave >= N_) return;
    int d = wave;
    float di = dinv[d];
    float acc = di * di * xin[(size_t)d * 64 + lane];   // self-loop
    int e0 = row_ptr[d];
    int e1 = row_ptr[d + 1];
    for (int eb = e0; eb < e1; eb += 64) {
        int   m  = min(64, e1 - eb);
        bool  ok = (eb + lane) < e1;
        int   cs = ok ? col[eb + lane] : 0;
        float vs = ok ? val[eb + lane] : 0.f;
        int j = 0;
        for (; j + 3 < m; j += 4) {
            int   s0 = __shfl(cs, j),     s1 = __shfl(cs, j + 1);
            int   s2 = __shfl(cs, j + 2), s3 = __shfl(cs, j + 3);
            float v0 = __shfl(vs, j),     v1 = __shfl(vs, j + 1);
            float v2 = __shfl(vs, j + 2), v3 = __shfl(vs, j + 3);
            float x0 = xin[(size_t)s0 * 64 + lane];
            float x1 = xin[(size_t)s1 * 64 + lane];
            float x2 = xin[(size_t)s2 * 64 + lane];
            float x3 = xin[(size_t)s3 * 64 + lane];
            acc = fmaf(v0, x0, acc);
            acc = fmaf(v1, x1, acc);
            acc = fmaf(v2, x2, acc);
            acc = fmaf(v3, x3, acc);
        }
        for (; j < m; ++j) {
            int   s = __shfl(cs, j);
            float v = __shfl(vs, j);
            acc = fmaf(v, xin[(size_t)s * 64 + lane], acc);
        }
    }
    xout[(size_t)d * 64 + lane] = acc;
}

// out[n][f] = relu( sum_k h[n][k] * W[f][k] + b[f] ), 64x64. One wave per node iter.
__global__ __launch_bounds__(256) void linear64_relu_kernel(const float* __restrict__ hin,
                                                            float* __restrict__ hout,
                                                            const float* __restrict__ W,
                                                            const float* __restrict__ b, int N_) {
    __shared__ float wl[64 * 65];   // pitch 65: bank = (lane+k)%32 -> conflict-free
    __shared__ float bl[64];
    for (int i = threadIdx.x; i < 64 * 64; i += 256) wl[(i >> 6) * 65 + (i & 63)] = W[i];
    if (threadIdx.x < 64) bl[threadIdx.x] = b[threadIdx.x];
    __syncthreads();
    int lane = threadIdx.x & 63;
    int gw = (blockIdx.x * blockDim.x + threadIdx.x) >> 6;
    int nw = (gridDim.x * blockDim.x) >> 6;
    for (int n = gw; n < N_; n += nw) {
        float hv = hin[(size_t)n * 64 + lane];
        float acc = bl[lane];
        #pragma unroll
        for (int k = 0; k < 64; ++k)
            acc = fmaf(__shfl(hv, k), wl[lane * 65 + k], acc);
        hout[(size_t)n * 64 + lane] = fmaxf(acc, 0.f);
    }
}

// out[n][f] = sum_k h[n][k] * W[f][k] + b[f], F_ <= 64 outputs.
__global__ __launch_bounds__(256) void linear_out_kernel(const float* __restrict__ hin,
                                                         float* __restrict__ out,
                                                         const float* __restrict__ W,
                                                         const float* __restrict__ b,
                                                         int N_, int F_) {
    __shared__ float wl[64 * 65];
    __shared__ float bl[64];
    for (int i = threadIdx.x; i < 64 * 65; i += 256) wl[i] = 0.f;   // zero pad rows >= F_
    __syncthreads();
    for (int i = threadIdx.x; i < F_ * 64; i += 256) wl[(i >> 6) * 65 + (i & 63)] = W[i];
    if (threadIdx.x < 64) bl[threadIdx.x] = (threadIdx.x < F_) ? b[threadIdx.x] : 0.f;
    __syncthreads();
    int lane = threadIdx.x & 63;
    int gw = (blockIdx.x * blockDim.x + threadIdx.x) >> 6;
    int nw = (gridDim.x * blockDim.x) >> 6;
    for (int n = gw; n < N_; n += nw) {
        float hv = hin[(size_t)n * 64 + lane];
        float acc = bl[lane];
        #pragma unroll
        for (int k = 0; k < 64; ++k)
            acc = fmaf(__shfl(hv, k), wl[lane * 65 + k], acc);
        if (lane < F_) out[(size_t)n * F_ + lane] = acc;
    }
}

extern "C" void kernel_launch(void* const* d_in, const int* in_sizes, int n_in,
                              void* d_out, int out_size, void* d_ws, size_t ws_size,
                              hipStream_t stream) {
    const float* x   = (const float*)d_in[0];
    const int*   ei  = (const int*)d_in[1];
    const float* w   = (const float*)d_in[2];
    const float* W1  = (const float*)d_in[3];
    const float* b1  = (const float*)d_in[4];
    const float* W2  = (const float*)d_in[5];
    const float* b2  = (const float*)d_in[6];
    float* out = (float*)d_out;

    const int N_ = in_sizes[0] / 64;        // 100000
    const int E_ = in_sizes[2];             // 1200000
    const int F_ = in_sizes[5] / 64;        // 40

    char* ws = (char*)d_ws;
    size_t off = 0;
    auto alloc = [&](size_t bytes) { size_t o = off; off += (bytes + 255) & ~(size_t)255; return o; };
    float* dinv    = (float*)(ws + alloc((size_t)N_ * 4));
    int*   cnt     = (int*)  (ws + alloc((size_t)N_ * 4));
    int*   row_ptr = (int*)  (ws + alloc(((size_t)N_ + 1) * 4));
    int*   bsums   = (int*)  (ws + alloc(1024 * 4));
    int*   col     = (int*)  (ws + alloc((size_t)E_ * 4));
    float* val     = (float*)(ws + alloc((size_t)E_ * 4));
    float* bufA    = (float*)(ws + alloc((size_t)N_ * 64 * 4));
    float* bufB    = (float*)(ws + alloc((size_t)N_ * 64 * 4));
    (void)ws_size; (void)n_in; (void)out_size;

    const int bn = (N_ + 255) / 256;
    const int be = (E_ + 255) / 256;
    const int bh = (N_ + 3) / 4;                      // 4 waves (nodes) per 256-thread block
    const int nb = (N_ + SCAN_CHUNK - 1) / SCAN_CHUNK; // 49 blocks for N=100k (<=1024)

    init_kernel<<<bn, 256, 0, stream>>>(dinv, cnt, N_);
    deg_count_kernel<<<be, 256, 0, stream>>>(ei, w, dinv, cnt, E_);
    rsqrt_kernel<<<bn, 256, 0, stream>>>(dinv, N_);
    scan_partial_kernel<<<nb, SCAN_TPB, 0, stream>>>(cnt, bsums, N_);
    scan_bsums_kernel<<<1, 1024, 0, stream>>>(bsums, nb, row_ptr, N_);
    scan_final_kernel<<<nb, SCAN_TPB, 0, stream>>>(cnt, bsums, row_ptr, N_);
    csr_fill_kernel<<<be, 256, 0, stream>>>(ei, w, dinv, row_ptr, cnt, col, val, E_);

    hop_kernel<<<bh, 256, 0, stream>>>(x,    bufA, dinv, row_ptr, col, val, N_);
    hop_kernel<<<bh, 256, 0, stream>>>(bufA, bufB, dinv, row_ptr, col, val, N_);
    linear64_relu_kernel<<<1024, 256, 0, stream>>>(bufB, bufA, W1, b1, N_);
    hop_kernel<<<bh, 256, 0, stream>>>(bufA, bufB, dinv, row_ptr, col, val, N_);
    hop_kernel<<<bh, 256, 0, stream>>>(bufB, bufA, dinv, row_ptr, col, val, N_);
    linear_out_kernel<<<1024, 256, 0, stream>>>(bufA, out, W2, b2, N_, F_);
}

// Round 3
// 494.750 us; speedup vs baseline: 1.7144x; 1.1303x over previous
//
#include <hip/hip_runtime.h>

// SGConv (K=2, two layers) on MI355X.
// R2: single-atomic CSR build (rank trick, no float atomics, no cursor atomics),
//     deg computed post-CSR by coalesced row reduction,
//     hop uses float4 gathers (4 rows / wave-instr) + quarter-wave reduction.

#define SCAN_TPB 256
#define SCAN_ITEMS 8
#define SCAN_CHUNK (SCAN_TPB * SCAN_ITEMS)   // 2048 elements per block

__global__ __launch_bounds__(256) void zero_cnt_kernel(int* cnt, int N_) {
    int n = blockIdx.x * blockDim.x + threadIdx.x;
    if (n < N_) cnt[n] = 0;
}

// rank[e] = arrival index of edge e within its dst bucket. ONLY atomic pass.
__global__ __launch_bounds__(256) void count_rank_kernel(const int* __restrict__ ei,
                                                         int* cnt, int* __restrict__ rank, int E_) {
    int e = blockIdx.x * blockDim.x + threadIdx.x;
    if (e < E_) rank[e] = atomicAdd(&cnt[ei[E_ + e]], 1);
}

// --- 3-phase hierarchical exclusive scan of cnt -> row_ptr ---

__global__ __launch_bounds__(SCAN_TPB) void scan_partial_kernel(const int* __restrict__ cnt,
                                                                int* __restrict__ bsums, int N_) {
    int t = threadIdx.x;
    int base = blockIdx.x * SCAN_CHUNK + t * SCAN_ITEMS;
    int s = 0;
    #pragma unroll
    for (int j = 0; j < SCAN_ITEMS; ++j) { int i = base + j; if (i < N_) s += cnt[i]; }
    __shared__ int sm[SCAN_TPB];
    sm[t] = s; __syncthreads();
    for (int o = SCAN_TPB / 2; o > 0; o >>= 1) {
        if (t < o) sm[t] += sm[t + o];
        __syncthreads();
    }
    if (t == 0) bsums[blockIdx.x] = sm[0];
}

__global__ __launch_bounds__(1024) void scan_bsums_kernel(int* bsums, int nb,
                                                          int* row_ptr, int N_) {
    __shared__ int sm[1024];
    int t = threadIdx.x;
    int v = (t < nb) ? bsums[t] : 0;
    sm[t] = v; __syncthreads();
    for (int o = 1; o < 1024; o <<= 1) {
        int u = (t >= o) ? sm[t - o] : 0;
        __syncthreads();
        sm[t] += u;
        __syncthreads();
    }
    if (t < nb) bsums[t] = sm[t] - v;          // exclusive block offset
    if (t == 1023) row_ptr[N_] = sm[1023];     // grand total
}

__global__ __launch_bounds__(SCAN_TPB) void scan_final_kernel(const int* __restrict__ cnt,
                                                              const int* __restrict__ bsums,
                                                              int* __restrict__ row_ptr, int N_) {
    int t = threadIdx.x;
    int base = blockIdx.x * SCAN_CHUNK + t * SCAN_ITEMS;
    int loc[SCAN_ITEMS];
    int s = 0;
    #pragma unroll
    for (int j = 0; j < SCAN_ITEMS; ++j) {
        int i = base + j;
        int c = (i < N_) ? cnt[i] : 0;
        loc[j] = s; s += c;
    }
    __shared__ int sm[SCAN_TPB];
    sm[t] = s; __syncthreads();
    for (int o = 1; o < SCAN_TPB; o <<= 1) {
        int u = (t >= o) ? sm[t - o] : 0;
        __syncthreads();
        sm[t] += u;
        __syncthreads();
    }
    int excl = bsums[blockIdx.x] + sm[t] - s;
    #pragma unroll
    for (int j = 0; j < SCAN_ITEMS; ++j) {
        int i = base + j;
        if (i < N_) row_ptr[i] = excl + loc[j];
    }
}

// Atomic-free CSR fill using precomputed ranks.
__global__ __launch_bounds__(256) void fill_kernel(const int* __restrict__ ei,
                                                   const float* __restrict__ w,
                                                   const int* __restrict__ row_ptr,
                                                   const int* __restrict__ rank,
                                                   int* __restrict__ col,
                                                   float* __restrict__ wv, int E_) {
    int e = blockIdx.x * blockDim.x + threadIdx.x;
    if (e < E_) {
        int d = ei[E_ + e];
        int pos = row_ptr[d] + rank[e];
        col[pos] = ei[e];
        wv[pos] = w[e];
    }
}

// deg[d] = 1 (self-loop) + sum of row d's weights; dinv = 1/sqrt(deg). Coalesced-ish rows.
__global__ __launch_bounds__(256) void deg_dinv_kernel(const float* __restrict__ wv,
                                                       const int* __restrict__ row_ptr,
                                                       float* __restrict__ dinv, int N_) {
    int n = blockIdx.x * blockDim.x + threadIdx.x;
    if (n < N_) {
        float s = 1.0f;
        int p0 = row_ptr[n], p1 = row_ptr[n + 1];
        for (int p = p0; p < p1; ++p) s += wv[p];
        dinv[n] = 1.0f / sqrtf(s);
    }
}

// val[pos] = dinv[src] * w * dinv[dst], written in place over wv.
__global__ __launch_bounds__(256) void scale_kernel(const int* __restrict__ ei,
                                                    const float* __restrict__ w,
                                                    const int* __restrict__ row_ptr,
                                                    const int* __restrict__ rank,
                                                    const float* __restrict__ dinv,
                                                    float* __restrict__ val, int E_) {
    int e = blockIdx.x * blockDim.x + threadIdx.x;
    if (e < E_) {
        int s = ei[e];
        int d = ei[E_ + e];
        int pos = row_ptr[d] + rank[e];
        val[pos] = dinv[s] * w[e] * dinv[d];
    }
}

// One wave per dst node. float4 gathers: quarter q of the wave fetches source row
// s_q (16 lanes x float4 = 256B row), so one wave-instruction covers 4 edges (1KB).
// Quarter partial sums combined by shfl_xor(16), shfl_xor(32) at the end.
__global__ __launch_bounds__(256) void hop_kernel(const float* __restrict__ xin,
                                                  float* __restrict__ xout,
                                                  const float* __restrict__ dinv,
                                                  const int* __restrict__ row_ptr,
                                                  const int* __restrict__ col,
                                                  const float* __restrict__ val, int N_) {
    int wave = (blockIdx.x * blockDim.x + threadIdx.x) >> 6;
    int lane = threadIdx.x & 63;
    if (wave >= N_) return;
    const int d  = wave;
    const int q  = lane >> 4;      // quarter 0..3
    const int fl = lane & 15;      // float4 slot within row

    int e0 = row_ptr[d], e1 = row_ptr[d + 1];
    int nE = e1 - e0;
    float di = dinv[d];
    float4 selfv = ((const float4*)(xin + (size_t)d * 64))[fl];   // prefetch self row
    float4 acc = make_float4(0.f, 0.f, 0.f, 0.f);

    for (int eb = 0; eb < nE; eb += 64) {
        int m = min(64, nE - eb);
        bool ok = lane < m;
        int   cs = ok ? col[e0 + eb + lane] : d;    // pad: self row, weight 0
        float vs = ok ? val[e0 + eb + lane] : 0.f;
        for (int g = 0; g < m; g += 8) {
            // two 4-edge groups in flight (slots g+q and g+4+q; both < 64 since g <= 56)
            int   s0 = __shfl(cs, g + q);
            int   s1 = __shfl(cs, g + 4 + q);
            float v0 = __shfl(vs, g + q);
            float v1 = __shfl(vs, g + 4 + q);
            float4 x0 = ((const float4*)(xin + (size_t)s0 * 64))[fl];
            float4 x1 = ((const float4*)(xin + (size_t)s1 * 64))[fl];
            acc.x = fmaf(v0, x0.x, acc.x); acc.y = fmaf(v0, x0.y, acc.y);
            acc.z = fmaf(v0, x0.z, acc.z); acc.w = fmaf(v0, x0.w, acc.w);
            acc.x = fmaf(v1, x1.x, acc.x); acc.y = fmaf(v1, x1.y, acc.y);
            acc.z = fmaf(v1, x1.z, acc.z); acc.w = fmaf(v1, x1.w, acc.w);
        }
    }
    // combine quarter partials: lanes {i, i+16, i+32, i+48} hold same features
    acc.x += __shfl_xor(acc.x, 16); acc.y += __shfl_xor(acc.y, 16);
    acc.z += __shfl_xor(acc.z, 16); acc.w += __shfl_xor(acc.w, 16);
    acc.x += __shfl_xor(acc.x, 32); acc.y += __shfl_xor(acc.y, 32);
    acc.z += __shfl_xor(acc.z, 32); acc.w += __shfl_xor(acc.w, 32);
    // self-loop
    float dii = di * di;
    acc.x = fmaf(dii, selfv.x, acc.x); acc.y = fmaf(dii, selfv.y, acc.y);
    acc.z = fmaf(dii, selfv.z, acc.z); acc.w = fmaf(dii, selfv.w, acc.w);
    if (lane < 16)
        ((float4*)(xout + (size_t)d * 64))[fl] = acc;
}

// out[n][f] = relu( sum_k h[n][k] * W[f][k] + b[f] ), 64x64. One wave per node iter.
__global__ __launch_bounds__(256) void linear64_relu_kernel(const float* __restrict__ hin,
                                                            float* __restrict__ hout,
                                                            const float* __restrict__ W,
                                                            const float* __restrict__ b, int N_) {
    __shared__ float wl[64 * 65];   // pitch 65: conflict-free
    __shared__ float bl[64];
    for (int i = threadIdx.x; i < 64 * 64; i += 256) wl[(i >> 6) * 65 + (i & 63)] = W[i];
    if (threadIdx.x < 64) bl[threadIdx.x] = b[threadIdx.x];
    __syncthreads();
    int lane = threadIdx.x & 63;
    int gw = (blockIdx.x * blockDim.x + threadIdx.x) >> 6;
    int nw = (gridDim.x * blockDim.x) >> 6;
    for (int n = gw; n < N_; n += nw) {
        float hv = hin[(size_t)n * 64 + lane];
        float acc = bl[lane];
        #pragma unroll
        for (int k = 0; k < 64; ++k)
            acc = fmaf(__shfl(hv, k), wl[lane * 65 + k], acc);
        hout[(size_t)n * 64 + lane] = fmaxf(acc, 0.f);
    }
}

// out[n][f] = sum_k h[n][k] * W[f][k] + b[f], F_ <= 64 outputs.
__global__ __launch_bounds__(256) void linear_out_kernel(const float* __restrict__ hin,
                                                         float* __restrict__ out,
                                                         const float* __restrict__ W,
                                                         const float* __restrict__ b,
                                                         int N_, int F_) {
    __shared__ float wl[64 * 65];
    __shared__ float bl[64];
    for (int i = threadIdx.x; i < 64 * 65; i += 256) wl[i] = 0.f;
    __syncthreads();
    for (int i = threadIdx.x; i < F_ * 64; i += 256) wl[(i >> 6) * 65 + (i & 63)] = W[i];
    if (threadIdx.x < 64) bl[threadIdx.x] = (threadIdx.x < F_) ? b[threadIdx.x] : 0.f;
    __syncthreads();
    int lane = threadIdx.x & 63;
    int gw = (blockIdx.x * blockDim.x + threadIdx.x) >> 6;
    int nw = (gridDim.x * blockDim.x) >> 6;
    for (int n = gw; n < N_; n += nw) {
        float hv = hin[(size_t)n * 64 + lane];
        float acc = bl[lane];
        #pragma unroll
        for (int k = 0; k < 64; ++k)
            acc = fmaf(__shfl(hv, k), wl[lane * 65 + k], acc);
        if (lane < F_) out[(size_t)n * F_ + lane] = acc;
    }
}

extern "C" void kernel_launch(void* const* d_in, const int* in_sizes, int n_in,
                              void* d_out, int out_size, void* d_ws, size_t ws_size,
                              hipStream_t stream) {
    const float* x   = (const float*)d_in[0];
    const int*   ei  = (const int*)d_in[1];
    const float* w   = (const float*)d_in[2];
    const float* W1  = (const float*)d_in[3];
    const float* b1  = (const float*)d_in[4];
    const float* W2  = (const float*)d_in[5];
    const float* b2  = (const float*)d_in[6];
    float* out = (float*)d_out;

    const int N_ = in_sizes[0] / 64;        // 100000
    const int E_ = in_sizes[2];             // 1200000
    const int F_ = in_sizes[5] / 64;        // 40

    char* ws = (char*)d_ws;
    size_t off = 0;
    auto alloc = [&](size_t bytes) { size_t o = off; off += (bytes + 255) & ~(size_t)255; return o; };
    float* dinv    = (float*)(ws + alloc((size_t)N_ * 4));
    int*   cnt     = (int*)  (ws + alloc((size_t)N_ * 4));
    int*   row_ptr = (int*)  (ws + alloc(((size_t)N_ + 1) * 4));
    int*   bsums   = (int*)  (ws + alloc(1024 * 4));
    int*   rank    = (int*)  (ws + alloc((size_t)E_ * 4));
    int*   col     = (int*)  (ws + alloc((size_t)E_ * 4));
    float* val     = (float*)(ws + alloc((size_t)E_ * 4));
    float* bufA    = (float*)(ws + alloc((size_t)N_ * 64 * 4));
    float* bufB    = (float*)(ws + alloc((size_t)N_ * 64 * 4));
    (void)ws_size; (void)n_in; (void)out_size;

    const int bn = (N_ + 255) / 256;
    const int be = (E_ + 255) / 256;
    const int bh = (N_ + 3) / 4;                       // 4 waves (nodes) per block
    const int nb = (N_ + SCAN_CHUNK - 1) / SCAN_CHUNK; // 49 blocks (<=1024)

    zero_cnt_kernel<<<bn, 256, 0, stream>>>(cnt, N_);
    count_rank_kernel<<<be, 256, 0, stream>>>(ei, cnt, rank, E_);
    scan_partial_kernel<<<nb, SCAN_TPB, 0, stream>>>(cnt, bsums, N_);
    scan_bsums_kernel<<<1, 1024, 0, stream>>>(bsums, nb, row_ptr, N_);
    scan_final_kernel<<<nb, SCAN_TPB, 0, stream>>>(cnt, bsums, row_ptr, N_);
    fill_kernel<<<be, 256, 0, stream>>>(ei, w, row_ptr, rank, col, val, E_);
    deg_dinv_kernel<<<bn, 256, 0, stream>>>(val, row_ptr, dinv, N_);
    scale_kernel<<<be, 256, 0, stream>>>(ei, w, row_ptr, rank, dinv, val, E_);

    hop_kernel<<<bh, 256, 0, stream>>>(x,    bufA, dinv, row_ptr, col, val, N_);
    hop_kernel<<<bh, 256, 0, stream>>>(bufA, bufB, dinv, row_ptr, col, val, N_);
    linear64_relu_kernel<<<1024, 256, 0, stream>>>(bufB, bufA, W1, b1, N_);
    hop_kernel<<<bh, 256, 0, stream>>>(bufA, bufB, dinv, row_ptr, col, val, N_);
    hop_kernel<<<bh, 256, 0, stream>>>(bufB, bufA, dinv, row_ptr, col, val, N_);
    linear_out_kernel<<<1024, 256, 0, stream>>>(bufA, out, W2, b2, N_, F_);
}